// Round 4
// baseline (333.941 us; speedup 1.0000x reference)
//
#include <hip/hip_runtime.h>
#include <hip/hip_bf16.h>

// MultiAgentGRULoop round 4: single barrier per cell.
//   - 256 blocks x 512 thr (8 waves); block owns 16 batch rows end-to-end;
//     layer-outer, d_out as inter-layer f32 activation buffer.
//   - Wave w holds bf16 B-frags for gate cols w*16+{0,128,256} in VGPRs.
//   - DOUBLE-BUFFERED s_h / s_act / s_in: cell reads [p], writes [p^1]
//     -> ONE __syncthreads per cell; global store+prefetch issued at cell
//     top drain at cell end (latency hidden under MFMA+epilogue).
//   - r,z gate accumulators fused (gi+gh+biases in one MFMA C-chain).
//   - h recurrence carried in f32 registers (exact); bf16 on MFMA paths only.

#define T_STEPS 64
#define HID 128
#define NL 3
#define RB 16
#define NTHR 512
#define NBLK 256
#define LSTR 136   // bf16 row stride (shorts): 272 B, 16B-aligned
#define ASTR 132   // f32 act row stride

typedef __attribute__((ext_vector_type(8))) short bf16x8;
typedef __attribute__((ext_vector_type(4))) short short4v;
typedef __attribute__((ext_vector_type(4))) float f32x4;

static __device__ __forceinline__ short f2bf_s(float f) {
  __hip_bfloat16 b = __float2bfloat16(f);
  return __builtin_bit_cast(short, b);
}
__device__ __forceinline__ float sigm(float v) { return 1.f / (1.f + __expf(-v)); }
__device__ __forceinline__ float tanh_f(float v) { return 1.f - 2.f / (__expf(2.f * v) + 1.f); }

__global__ __launch_bounds__(NTHR, 1) void gru4(
    const float* __restrict__ x, const int* __restrict__ invalid,
    const float* __restrict__ w_ih, const float* __restrict__ w_hh,
    const float* __restrict__ b_ih, const float* __restrict__ b_hh,
    float* out)
{
  __shared__ short s_in[2][RB * LSTR];   // input bf16 (x[t], x[t+1])
  __shared__ short s_h[2][RB * LSTR];    // h bf16 (masked), double-buffered
  __shared__ float s_act[2][RB * ASTR];  // f32 activation out-staging, dbuf
  __shared__ int   s_msk[RB * T_STEPS];  // invalid mask for the block's rows

  const int tid = threadIdx.x;
  const int wave = tid >> 6, lane = tid & 63;
  const int lr = lane & 15, lq = lane >> 4;
  const int row_base = (int)blockIdx.x * RB;
  const int srow = tid >> 5, scol = (tid & 31) * 4;  // coalesced f32x4 map

  for (int i = tid; i < RB * T_STEPS; i += NTHR)
    s_msk[i] = invalid[(size_t)row_base * T_STEPS + i];

  for (int l = 0; l < NL; ++l) {
    // ---- per layer: weights -> bf16 register B-fragments ----
    bf16x8 wI[3][4], wH[3][4];
#pragma unroll
    for (int g = 0; g < 3; ++g)
#pragma unroll
      for (int kf = 0; kf < 4; ++kf) {
        const int wrow = g * HID + wave * 16 + lr;  // B col = lane&15
        const int kofs = kf * 32 + lq * 8;          // k-map identical to A side
        const float* pI = w_ih + ((size_t)l * 3 * HID + wrow) * HID + kofs;
        const float* pH = w_hh + ((size_t)l * 3 * HID + wrow) * HID + kofs;
        float4 a = *(const float4*)pI, b = *(const float4*)(pI + 4);
        float vi[8] = {a.x, a.y, a.z, a.w, b.x, b.y, b.z, b.w};
        float4 c = *(const float4*)pH, d = *(const float4*)(pH + 4);
        float vh[8] = {c.x, c.y, c.z, c.w, d.x, d.y, d.z, d.w};
#pragma unroll
        for (int j = 0; j < 8; ++j) {
          wI[g][kf][j] = f2bf_s(vi[j]);
          wH[g][kf][j] = f2bf_s(vh[j]);
        }
      }
    float bRZ[2], bIn, bHn;
#pragma unroll
    for (int g = 0; g < 2; ++g)
      bRZ[g] = b_ih[l * 3 * HID + g * HID + wave * 16 + lr] +
               b_hh[l * 3 * HID + g * HID + wave * 16 + lr];
    bIn = b_ih[l * 3 * HID + 2 * HID + wave * 16 + lr];
    bHn = b_hh[l * 3 * HID + 2 * HID + wave * 16 + lr];

    // ---- h := 0, stage input[t=0] into buffer 0 ----
    for (int i = tid; i < RB * LSTR; i += NTHR) s_h[0][i] = 0;
    float hprev[4] = {0.f, 0.f, 0.f, 0.f};
    const float* src = (l == 0) ? x : (const float*)out;
    {
      float4 v = *(const float4*)(src + ((size_t)(row_base + srow) * T_STEPS + 0) * HID + scol);
      short4v c4 = {f2bf_s(v.x), f2bf_s(v.y), f2bf_s(v.z), f2bf_s(v.w)};
      *(short4v*)&s_in[0][srow * LSTR + scol] = c4;
    }
    __syncthreads();

#pragma unroll 2
    for (int t = 0; t < T_STEPS; ++t) {
      const int p = t & 1;
      // ---- deferred store of step t-1 activations (drains at cell-end barrier) ----
      if (t > 0) {
        float4 a = *(const float4*)&s_act[p][srow * ASTR + scol];
        *(float4*)(out + ((size_t)(row_base + srow) * T_STEPS + (t - 1)) * HID + scol) = a;
      }
      // ---- prefetch next-step input + this-step masks (hidden under MFMA) ----
      float4 pin = make_float4(0.f, 0.f, 0.f, 0.f);
      if (t < T_STEPS - 1)
        pin = *(const float4*)(src + ((size_t)(row_base + srow) * T_STEPS + (t + 1)) * HID + scol);
      int mk[4];
#pragma unroll
      for (int ri = 0; ri < 4; ++ri) mk[ri] = s_msk[(lq * 4 + ri) * T_STEPS + t];

      // ---- MFMA phase: bias-initialized accumulators, r/z fused ----
      f32x4 aRZ0 = (f32x4)(bRZ[0]), aRZ1 = (f32x4)(bRZ[1]);
      f32x4 aN = (f32x4)(bIn), aHn = (f32x4)(bHn);
#pragma unroll
      for (int kf = 0; kf < 4; ++kf) {
        const int ao = lr * LSTR + kf * 32 + lq * 8;  // A row = lane&15
        bf16x8 xh = *(const bf16x8*)&s_in[p][ao];
        bf16x8 hh = *(const bf16x8*)&s_h[p][ao];
        aRZ0 = __builtin_amdgcn_mfma_f32_16x16x32_bf16(xh, wI[0][kf], aRZ0, 0, 0, 0);
        aRZ0 = __builtin_amdgcn_mfma_f32_16x16x32_bf16(hh, wH[0][kf], aRZ0, 0, 0, 0);
        aRZ1 = __builtin_amdgcn_mfma_f32_16x16x32_bf16(xh, wI[1][kf], aRZ1, 0, 0, 0);
        aRZ1 = __builtin_amdgcn_mfma_f32_16x16x32_bf16(hh, wH[1][kf], aRZ1, 0, 0, 0);
        aN   = __builtin_amdgcn_mfma_f32_16x16x32_bf16(xh, wI[2][kf], aN, 0, 0, 0);
        aHn  = __builtin_amdgcn_mfma_f32_16x16x32_bf16(hh, wH[2][kf], aHn, 0, 0, 0);
      }

      // ---- epilogue: lane owns (rows lq*4+ri, col wave*16+lr); writes [p^1] ----
#pragma unroll
      for (int ri = 0; ri < 4; ++ri) {
        const int row = lq * 4 + ri;
        float rr = sigm(aRZ0[ri]);
        float zz = sigm(aRZ1[ri]);
        float nn = tanh_f(aN[ri] + rr * aHn[ri]);
        float hn = nn + zz * (hprev[ri] - nn);
        float hm = mk[ri] ? 0.f : hn;
        hprev[ri] = hm;
        // layers 0/1 pass UNMASKED h; final layer emits masked y
        s_act[p ^ 1][row * ASTR + wave * 16 + lr] = (l == NL - 1) ? hm : hn;
        s_h[p ^ 1][row * LSTR + wave * 16 + lr] = f2bf_s(hm);
      }
      if (t < T_STEPS - 1) {
        short4v c4 = {f2bf_s(pin.x), f2bf_s(pin.y), f2bf_s(pin.z), f2bf_s(pin.w)};
        *(short4v*)&s_in[p ^ 1][srow * LSTR + scol] = c4;
      }
      __syncthreads();  // ONE barrier: all [p^1] writes visible, vmcnt drained
    }
    // ---- flush t=63 activations (live in s_act[0]: (63&1)^1 == 0) ----
    {
      float4 a = *(const float4*)&s_act[0][srow * ASTR + scol];
      *(float4*)(out + ((size_t)(row_base + srow) * T_STEPS + (T_STEPS - 1)) * HID + scol) = a;
    }
    __syncthreads();  // out-writes drained+visible before next layer stages from out
  }
}

extern "C" void kernel_launch(void* const* d_in, const int* in_sizes, int n_in,
                              void* d_out, int out_size, void* d_ws, size_t ws_size,
                              hipStream_t stream) {
  const float* x       = (const float*)d_in[0];
  const int*   invalid = (const int*)d_in[1];
  const float* w_ih    = (const float*)d_in[2];
  const float* w_hh    = (const float*)d_in[3];
  const float* b_ih    = (const float*)d_in[4];
  const float* b_hh    = (const float*)d_in[5];
  gru4<<<dim3(NBLK), dim3(NTHR), 0, stream>>>(x, invalid, w_ih, w_hh, b_ih, b_hh,
                                              (float*)d_out);
}